// Round 10
// baseline (527.655 us; speedup 1.0000x reference)
//
#include <hip/hip_runtime.h>
#include <hip/hip_fp16.h>

#define IN_F 128
#define HID 256
#define HID2 128

typedef __attribute__((ext_vector_type(8))) _Float16 f16x8;
typedef __attribute__((ext_vector_type(4))) float f32x4;

// =================== K1: fused prep + CSR build ===================
// grid = 1024 blocks x 256 threads. DIY device-scope grid barrier needs all
// blocks co-resident: VGPR=24, LDS=512B -> 8 blocks/CU capacity, we need 4.
// (R9 used 256 blocks = 1 wave/SIMD: latency-bound phases ran 3x slower than
// the separate kernels they replaced. 1024 restores 4 waves/SIMD.)
__device__ __forceinline__ void grid_bar(int* cnt, int target) {
    __syncthreads();
    if (threadIdx.x == 0) {
        __hip_atomic_fetch_add(cnt, 1, __ATOMIC_ACQ_REL, __HIP_MEMORY_SCOPE_AGENT);
        while (__hip_atomic_load(cnt, __ATOMIC_ACQUIRE, __HIP_MEMORY_SCOPE_AGENT) < target)
            __builtin_amdgcn_s_sleep(8);
    }
    __syncthreads();
}

__global__ __launch_bounds__(256) void build_all(
        const float* __restrict__ x, const int* __restrict__ row, const int* __restrict__ col,
        const float* __restrict__ W1, const float* __restrict__ W2,
        ushort* __restrict__ xh, ushort* __restrict__ w1h, ushort* __restrict__ w1l,
        ushort* __restrict__ w2h, ushort* __restrict__ w2l,
        int* __restrict__ deg, int* __restrict__ fill, int* __restrict__ part, int* __restrict__ cnt,
        int* __restrict__ rp, int* __restrict__ csr, int N, int E) {
    int b = blockIdx.x, t = threadIdx.x;
    int gid = b * 256 + t, gsz = gridDim.x * 256;
    int G = gridDim.x;

    // phase 0: x -> fp16 (8/thread), W split fp16 hi/lo, count degrees
    int t8 = N * IN_F / 8;
    for (int i = gid; i < t8; i += gsz) {
        const float4* s4 = (const float4*)x + (size_t)i * 2;
        float4 f0 = s4[0], f1 = s4[1];
        uint4 o;
        o.x = __half_as_ushort(__float2half(f0.x)) | ((unsigned)__half_as_ushort(__float2half(f0.y)) << 16);
        o.y = __half_as_ushort(__float2half(f0.z)) | ((unsigned)__half_as_ushort(__float2half(f0.w)) << 16);
        o.z = __half_as_ushort(__float2half(f1.x)) | ((unsigned)__half_as_ushort(__float2half(f1.y)) << 16);
        o.w = __half_as_ushort(__float2half(f1.z)) | ((unsigned)__half_as_ushort(__float2half(f1.w)) << 16);
        ((uint4*)xh)[i] = o;
    }
    int nw = HID * IN_F + HID2 * HID;   // 65536
    for (int i = gid; i < nw; i += gsz) {
        bool first = i < HID * IN_F;
        int j = first ? i : i - HID * IN_F;
        float f = first ? W1[j] : W2[j];
        __half h = __float2half(f);
        __half lo = __float2half(f - __half2float(h));
        if (first) { w1h[j] = __half_as_ushort(h); w1l[j] = __half_as_ushort(lo); }
        else       { w2h[j] = __half_as_ushort(h); w2l[j] = __half_as_ushort(lo); }
    }
    for (int e = gid; e < E; e += gsz) atomicAdd(&deg[col[e]], 1);
    grid_bar(cnt, G);

    // phase 1: per-block inclusive scan of 256-elem slices (blocks 0..195)
    int lane = t & 63, w = t >> 6;
    __shared__ int ws[4];
    int locinc = 0;
    int nb = (N + 255) / 256;           // 196
    if (b < nb) {
        int i = b * 256 + t;
        int v = (i < N) ? deg[i] : 0;
        int xv = v;
#pragma unroll
        for (int d = 1; d < 64; d <<= 1) {
            int y = __shfl_up(xv, d, 64);
            if (lane >= d) xv += y;
        }
        if (lane == 63) ws[w] = xv;
        __syncthreads();
        if (t < 4) {
            int s = ws[t];
#pragma unroll
            for (int d = 1; d < 4; d <<= 1) {
                int y = __shfl_up(s, d, 64);
                if (t >= d) s += y;
            }
            ws[t] = s;
        }
        __syncthreads();
        locinc = xv + (w ? ws[w - 1] : 0);
        if (t == 255) part[b] = locinc;
    }
    grid_bar(cnt, 2 * G);

    // phase 2: block 0 scans the 196 partials
    if (b == 0) {
        int v = (t < nb) ? part[t] : 0;
        int xv = v;
#pragma unroll
        for (int d = 1; d < 64; d <<= 1) {
            int y = __shfl_up(xv, d, 64);
            if (lane >= d) xv += y;
        }
        __syncthreads();
        if (lane == 63) ws[w] = xv;
        __syncthreads();
        if (t < 4) {
            int s = ws[t];
#pragma unroll
            for (int d = 1; d < 4; d <<= 1) {
                int y = __shfl_up(s, d, 64);
                if (t >= d) s += y;
            }
            ws[t] = s;
        }
        __syncthreads();
        xv += (w ? ws[w - 1] : 0);
        if (t < nb) part[t] = xv;
    }
    grid_bar(cnt, 3 * G);

    // phase 3: write rp
    if (b < nb) {
        int i = b * 256 + t;
        int off = b ? part[b - 1] : 0;
        if (i < N) rp[i + 1] = locinc + off;
        if (i == 0) rp[0] = 0;
    }
    grid_bar(cnt, 4 * G);

    // phase 4: fill CSR
    for (int e = gid; e < E; e += gsz) {
        int c = col[e];
        int p = atomicAdd(&fill[c], 1);
        csr[rp[c] + p] = row[e];
    }
}

// unpack uint2 (4 fp16) and accumulate into float4
__device__ __forceinline__ void add4h(float4& a, uint2 v) {
    float2 f0 = __half22float2(*(const __half2*)&v.x);
    float2 f1 = __half22float2(*(const __half2*)&v.y);
    a.x += f0.x; a.y += f0.y; a.z += f1.x; a.w += f1.y;
}

// ------- Layer 1 agg (R8-proven skeleton): wave-per-node, 32 lanes/row (uint2),
//         2 edges/step, 4-deep unroll. fp16 in, fp16 out. -------
__global__ __launch_bounds__(256) void agg_gather(const ushort* __restrict__ xh,
                                                  const int* __restrict__ rp,
                                                  const int* __restrict__ csr,
                                                  ushort* __restrict__ outh, int N) {
    int w = threadIdx.x >> 6, lane = threadIdx.x & 63;
    int n = blockIdx.x * 4 + w;
    if (n >= N) return;
    int s = rp[n], e = rp[n + 1];
    int half = lane >> 5, l = lane & 31;
    const uint2* xv = (const uint2*)xh;   // row = 32 uint2
    float4 a0 = {0,0,0,0}, a1 = {0,0,0,0}, a2 = {0,0,0,0}, a3 = {0,0,0,0};
    int i = s;
    for (; i + 7 < e; i += 8) {
        int s0 = csr[i + half], s1 = csr[i + 2 + half];
        int s2 = csr[i + 4 + half], s3 = csr[i + 6 + half];
        uint2 v0 = xv[(size_t)s0 * 32 + l];
        uint2 v1 = xv[(size_t)s1 * 32 + l];
        uint2 v2 = xv[(size_t)s2 * 32 + l];
        uint2 v3 = xv[(size_t)s3 * 32 + l];
        add4h(a0, v0); add4h(a1, v1); add4h(a2, v2); add4h(a3, v3);
    }
    for (; i + 1 < e; i += 2) {
        add4h(a0, xv[(size_t)csr[i + half] * 32 + l]);
    }
    if (i < e && half == 0) {
        add4h(a0, xv[(size_t)csr[i] * 32 + l]);
    }
    a0.x += a1.x + a2.x + a3.x; a0.y += a1.y + a2.y + a3.y;
    a0.z += a1.z + a2.z + a3.z; a0.w += a1.w + a2.w + a3.w;
    a0.x += __shfl_xor(a0.x, 32, 64);
    a0.y += __shfl_xor(a0.y, 32, 64);
    a0.z += __shfl_xor(a0.z, 32, 64);
    a0.w += __shfl_xor(a0.w, 32, 64);
    if (half == 0) {
        float dinv = 1.f / fmaxf((float)(e - s), 1.f);
        uint2 o;
        o.x = __half_as_ushort(__float2half(a0.x * dinv)) |
              ((unsigned)__half_as_ushort(__float2half(a0.y * dinv)) << 16);
        o.y = __half_as_ushort(__float2half(a0.z * dinv)) |
              ((unsigned)__half_as_ushort(__float2half(a0.w * dinv)) << 16);
        ((uint2*)outh)[(size_t)n * 32 + l] = o;
    }
}

// ---------------- fp16 MFMA GEMM: C[M,N] = A @ W^T (+bias,relu), fp16 out ----------------
// 2-pass split: A*(Wh+Wl), Wl = f16 residual of fp32 w -> ~2^-22 weight error.
// 4 waves in 2x2 over (32*MI)x(32*NJ) tile; MI x NJ mfma_f32_16x16x32_f16 per wave.
// Fragments straight from global (k-major both sides). Double-buffered register
// prefetch of next K-chunk. K % 64 == 0.
// C/D layout: col = lane&15, row = (lane>>4)*4 + reg.
template<int MI, int NJ, bool RELU_BIAS>
__global__ __launch_bounds__(256) void gemm_f16(const ushort* __restrict__ A,
                                                const ushort* __restrict__ Wh,
                                                const ushort* __restrict__ Wl,
                                                const float* __restrict__ bias,
                                                ushort* __restrict__ C,
                                                int M, int N, int K) {
    int t = threadIdx.x;
    int wv = t >> 6, l = t & 63;
    int r = l & 15, q = l >> 4;
    int m0 = blockIdx.x * (32 * MI) + (wv >> 1) * (16 * MI);
    int n0 = blockIdx.y * (32 * NJ) + (wv & 1) * (16 * NJ);
    const _Float16* Af = (const _Float16*)A;
    const _Float16* Whf = (const _Float16*)Wh;
    const _Float16* Wlf = (const _Float16*)Wl;

    f32x4 acc[MI][NJ];
#pragma unroll
    for (int i = 0; i < MI; i++)
#pragma unroll
        for (int j = 0; j < NJ; j++) acc[i][j] = (f32x4){0.f, 0.f, 0.f, 0.f};

    f16x8 a0[MI], h0[NJ], l0[NJ], a1[MI], h1_[NJ], l1_[NJ];

    auto load = [&](f16x8* a, f16x8* wh, f16x8* wl, int k0) {
        int kf = k0 + q * 8;
#pragma unroll
        for (int i = 0; i < MI; i++) {
            int m = m0 + 16 * i + r;
            if (m > M - 1) m = M - 1;           // clamp tail (stores guarded)
            a[i] = *(const f16x8*)(Af + (size_t)m * K + kf);
        }
#pragma unroll
        for (int j = 0; j < NJ; j++) {
            size_t wo = (size_t)(n0 + 16 * j + r) * K + kf;
            wh[j] = *(const f16x8*)(Whf + wo);
            wl[j] = *(const f16x8*)(Wlf + wo);
        }
    };
    auto mm = [&](f16x8* a, f16x8* wh, f16x8* wl) {
#pragma unroll
        for (int i = 0; i < MI; i++)
#pragma unroll
            for (int j = 0; j < NJ; j++) {
                acc[i][j] = __builtin_amdgcn_mfma_f32_16x16x32_f16(a[i], wh[j], acc[i][j], 0, 0, 0);
                acc[i][j] = __builtin_amdgcn_mfma_f32_16x16x32_f16(a[i], wl[j], acc[i][j], 0, 0, 0);
            }
    };

    load(a0, h0, l0, 0);
    for (int k0 = 0; k0 < K; k0 += 64) {
        load(a1, h1_, l1_, k0 + 32);
        mm(a0, h0, l0);
        if (k0 + 64 < K) load(a0, h0, l0, k0 + 64);
        mm(a1, h1_, l1_);
    }

#pragma unroll
    for (int i = 0; i < MI; i++) {
#pragma unroll
        for (int reg = 0; reg < 4; reg++) {
            int m = m0 + 16 * i + q * 4 + reg;
            if (m < M) {
#pragma unroll
                for (int j = 0; j < NJ; j++) {
                    int n = n0 + 16 * j + r;
                    float v = acc[i][j][reg];
                    if (RELU_BIAS) v = fmaxf(v + bias[n], 0.f);
                    C[(size_t)m * N + n] = __half_as_ushort(__float2half(v));
                }
            }
        }
    }
}

// ------- Layer 2 agg (R8-proven): fp16 z table + fused bias+relu + [128]->[2] GEMM -------
__global__ __launch_bounds__(256) void agg2_out(const ushort* __restrict__ zh,
                                                const int* __restrict__ rp,
                                                const int* __restrict__ csr,
                                                const float* __restrict__ b2,
                                                const float* __restrict__ W3,
                                                const float* __restrict__ b3,
                                                float* __restrict__ out, int N) {
    int w = threadIdx.x >> 6, lane = threadIdx.x & 63;
    int n = blockIdx.x * 4 + w;
    if (n >= N) return;
    int s = rp[n], e = rp[n + 1];
    int half = lane >> 5, l = lane & 31;
    const uint2* zv = (const uint2*)zh;
    float4 a0 = {0,0,0,0}, a1 = {0,0,0,0}, a2 = {0,0,0,0}, a3 = {0,0,0,0};
    int i = s;
    for (; i + 7 < e; i += 8) {
        int s0 = csr[i + half], s1 = csr[i + 2 + half];
        int s2 = csr[i + 4 + half], s3 = csr[i + 6 + half];
        uint2 v0 = zv[(size_t)s0 * 32 + l];
        uint2 v1 = zv[(size_t)s1 * 32 + l];
        uint2 v2 = zv[(size_t)s2 * 32 + l];
        uint2 v3 = zv[(size_t)s3 * 32 + l];
        add4h(a0, v0); add4h(a1, v1); add4h(a2, v2); add4h(a3, v3);
    }
    for (; i + 1 < e; i += 2) {
        add4h(a0, zv[(size_t)csr[i + half] * 32 + l]);
    }
    if (i < e && half == 0) {
        add4h(a0, zv[(size_t)csr[i] * 32 + l]);
    }
    a0.x += a1.x + a2.x + a3.x; a0.y += a1.y + a2.y + a3.y;
    a0.z += a1.z + a2.z + a3.z; a0.w += a1.w + a2.w + a3.w;
    a0.x += __shfl_xor(a0.x, 32, 64);
    a0.y += __shfl_xor(a0.y, 32, 64);
    a0.z += __shfl_xor(a0.z, 32, 64);
    a0.w += __shfl_xor(a0.w, 32, 64);
    float dinv = 1.f / fmaxf((float)(e - s), 1.f);
    float4 bb = ((const float4*)b2)[l];
    float4 ww = ((const float4*)W3)[half * 32 + l];
    float hx = fmaxf(a0.x * dinv + bb.x, 0.f);
    float hy = fmaxf(a0.y * dinv + bb.y, 0.f);
    float hz = fmaxf(a0.z * dinv + bb.z, 0.f);
    float hw = fmaxf(a0.w * dinv + bb.w, 0.f);
    float p = hx * ww.x + hy * ww.y + hz * ww.z + hw * ww.w;
#pragma unroll
    for (int d = 16; d > 0; d >>= 1) p += __shfl_xor(p, d, 64);
    if (l == 0) out[(size_t)n * 2 + half] = p + b3[half];
}

extern "C" void kernel_launch(void* const* d_in, const int* in_sizes, int n_in,
                              void* d_out, int out_size, void* d_ws, size_t ws_size,
                              hipStream_t stream) {
    const float* x  = (const float*)d_in[0];
    const int*   ei = (const int*)d_in[1];
    const float* W1 = (const float*)d_in[3];
    const float* b1 = (const float*)d_in[4];
    const float* W2 = (const float*)d_in[5];
    const float* b2 = (const float*)d_in[6];
    const float* W3 = (const float*)d_in[7];
    const float* b3 = (const float*)d_in[8];
    float* out = (float*)d_out;

    int N = in_sizes[0] / IN_F;   // 50000
    int E = in_sizes[1] / 2;      // 800000
    const int* row = ei;
    const int* col = ei + E;

    char* base = (char*)d_ws;
    size_t off = 0;
    auto alloc = [&](size_t bytes) -> void* {
        off = (off + 255) & ~(size_t)255;
        void* p = base + off;
        off += bytes;
        return p;
    };
    // zeroed region: deg | fill | part(1024) | cnt(1)
    int*    deg  = (int*)alloc(((size_t)2 * N + 1025) * 4);
    int*    fill = deg + N;
    int*    part = fill + N;
    int*    cnt  = part + 1024;
    int*    rp   = (int*)alloc((size_t)(N + 1) * 4);
    int*    csr  = (int*)alloc((size_t)E * 4);
    ushort* xh   = (ushort*)alloc((size_t)N * IN_F * 2);
    ushort* f2h  = (ushort*)alloc((size_t)N * IN_F * 2);   // agg1 out fp16
    ushort* h1h  = (ushort*)alloc((size_t)N * HID * 2);    // layer1 out fp16
    ushort* z2h  = (ushort*)alloc((size_t)N * HID2 * 2);   // gemm2 out fp16
    ushort* w1h  = (ushort*)alloc(HID * IN_F * 2);
    ushort* w1l  = (ushort*)alloc(HID * IN_F * 2);
    ushort* w2h  = (ushort*)alloc(HID2 * HID * 2);
    ushort* w2l  = (ushort*)alloc(HID2 * HID * 2);

    hipMemsetAsync(deg, 0, ((size_t)2 * N + 1025) * 4, stream);

    build_all<<<1024, 256, 0, stream>>>(x, row, col, W1, W2, xh, w1h, w1l, w2h, w2l,
                                        deg, fill, part, cnt, rp, csr, N, E);

    agg_gather<<<(N + 3) / 4, 256, 0, stream>>>(xh, rp, csr, f2h, N);

    // gemm1: 128x128 tiles, grid (391, 2); gemm2: 64x64 tiles, grid (782, 2)
    gemm_f16<4, 4, true><<<dim3((N + 127) / 128, HID / 128), 256, 0, stream>>>(
        f2h, w1h, w1l, b1, h1h, N, HID, IN_F);
    gemm_f16<2, 2, false><<<dim3((N + 63) / 64, HID2 / 64), 256, 0, stream>>>(
        h1h, w2h, w2l, nullptr, z2h, N, HID2, HID);

    agg2_out<<<(N + 3) / 4, 256, 0, stream>>>(z2h, rp, csr, b2, W3, b3, out, N);
}

// Round 11
// 310.869 us; speedup vs baseline: 1.6974x; 1.6974x over previous
//
#include <hip/hip_runtime.h>
#include <hip/hip_fp16.h>

#define IN_F 128
#define HID 256
#define HID2 128

typedef __attribute__((ext_vector_type(8))) _Float16 f16x8;
typedef __attribute__((ext_vector_type(4))) float f32x4;

// =================== prep: x->fp16, W1/W2 split fp16 hi/lo, count degrees ===================
// Barrier-free fusion of three independent grid-stride loops (R10 lesson: DIY
// grid barriers cost more than the launch gaps they save; fuse ONLY barrier-free).
__global__ __launch_bounds__(256) void prep(
        const float* __restrict__ x, const int* __restrict__ col,
        const float* __restrict__ W1, const float* __restrict__ W2,
        ushort* __restrict__ xh, ushort* __restrict__ w1h, ushort* __restrict__ w1l,
        ushort* __restrict__ w2h, ushort* __restrict__ w2l,
        int* __restrict__ deg, int N, int E) {
    int gid = blockIdx.x * 256 + threadIdx.x, gsz = gridDim.x * 256;
    int t8 = N * IN_F / 8;
    for (int i = gid; i < t8; i += gsz) {
        const float4* s4 = (const float4*)x + (size_t)i * 2;
        float4 f0 = s4[0], f1 = s4[1];
        uint4 o;
        o.x = __half_as_ushort(__float2half(f0.x)) | ((unsigned)__half_as_ushort(__float2half(f0.y)) << 16);
        o.y = __half_as_ushort(__float2half(f0.z)) | ((unsigned)__half_as_ushort(__float2half(f0.w)) << 16);
        o.z = __half_as_ushort(__float2half(f1.x)) | ((unsigned)__half_as_ushort(__float2half(f1.y)) << 16);
        o.w = __half_as_ushort(__float2half(f1.z)) | ((unsigned)__half_as_ushort(__float2half(f1.w)) << 16);
        ((uint4*)xh)[i] = o;
    }
    int nw = HID * IN_F + HID2 * HID;   // 65536
    for (int i = gid; i < nw; i += gsz) {
        bool first = i < HID * IN_F;
        int j = first ? i : i - HID * IN_F;
        float f = first ? W1[j] : W2[j];
        __half h = __float2half(f);
        __half lo = __float2half(f - __half2float(h));
        if (first) { w1h[j] = __half_as_ushort(h); w1l[j] = __half_as_ushort(lo); }
        else       { w2h[j] = __half_as_ushort(h); w2l[j] = __half_as_ushort(lo); }
    }
    for (int e = gid; e < E; e += gsz) atomicAdd(&deg[col[e]], 1);
}

// =================== 3-phase parallel scan (R8-proven) ===================
__global__ __launch_bounds__(256) void scan_block(const int* __restrict__ deg,
                                                  int* __restrict__ tmp,
                                                  int* __restrict__ bsum, int n) {
    int b = blockIdx.x, t = threadIdx.x, i = b * 256 + t;
    int lane = t & 63, w = t >> 6;
    int v = (i < n) ? deg[i] : 0;
    int x = v;
#pragma unroll
    for (int d = 1; d < 64; d <<= 1) {
        int y = __shfl_up(x, d, 64);
        if (lane >= d) x += y;
    }
    __shared__ int ws[4];
    if (lane == 63) ws[w] = x;
    __syncthreads();
    if (t < 4) {
        int s = ws[t];
#pragma unroll
        for (int d = 1; d < 4; d <<= 1) {
            int y = __shfl_up(s, d, 64);
            if (t >= d) s += y;
        }
        ws[t] = s;
    }
    __syncthreads();
    x += (w ? ws[w - 1] : 0);
    if (i < n) tmp[i] = x;
    if (t == 255) bsum[b] = x;
}

__global__ __launch_bounds__(256) void scan_bsums(int* __restrict__ bsum, int nb) {
    int t = threadIdx.x, lane = t & 63, w = t >> 6;
    int v = (t < nb) ? bsum[t] : 0;
    int x = v;
#pragma unroll
    for (int d = 1; d < 64; d <<= 1) {
        int y = __shfl_up(x, d, 64);
        if (lane >= d) x += y;
    }
    __shared__ int ws[4];
    if (lane == 63) ws[w] = x;
    __syncthreads();
    if (t < 4) {
        int s = ws[t];
#pragma unroll
        for (int d = 1; d < 4; d <<= 1) {
            int y = __shfl_up(s, d, 64);
            if (t >= d) s += y;
        }
        ws[t] = s;
    }
    __syncthreads();
    x += (w ? ws[w - 1] : 0);
    if (t < nb) bsum[t] = x;
}

__global__ void scan_add(const int* __restrict__ tmp, const int* __restrict__ bsum,
                         int* __restrict__ rp, int n) {
    int b = blockIdx.x, i = b * 256 + threadIdx.x;
    if (i < n) {
        rp[i + 1] = tmp[i] + (b ? bsum[b - 1] : 0);
        if (i == 0) rp[0] = 0;
    }
}

__global__ void fill_csr(const int* __restrict__ row, const int* __restrict__ col,
                         const int* __restrict__ rp, int* __restrict__ fill,
                         int* __restrict__ csr, int E) {
    int e = blockIdx.x * blockDim.x + threadIdx.x;
    if (e < E) {
        int c = col[e];
        int p = atomicAdd(&fill[c], 1);
        csr[rp[c] + p] = row[e];
    }
}

// unpack uint2 (4 fp16) and accumulate into float4
__device__ __forceinline__ void add4h(float4& a, uint2 v) {
    float2 f0 = __half22float2(*(const __half2*)&v.x);
    float2 f1 = __half22float2(*(const __half2*)&v.y);
    a.x += f0.x; a.y += f0.y; a.z += f1.x; a.w += f1.y;
}

// ------- Layer 1 agg (R8/R9-proven): wave-per-node, 32 lanes/row (uint2),
//         2 edges/step, 4-deep unroll. fp16 in, fp16 out. -------
__global__ __launch_bounds__(256) void agg_gather(const ushort* __restrict__ xh,
                                                  const int* __restrict__ rp,
                                                  const int* __restrict__ csr,
                                                  ushort* __restrict__ outh, int N) {
    int w = threadIdx.x >> 6, lane = threadIdx.x & 63;
    int n = blockIdx.x * 4 + w;
    if (n >= N) return;
    int s = rp[n], e = rp[n + 1];
    int half = lane >> 5, l = lane & 31;
    const uint2* xv = (const uint2*)xh;   // row = 32 uint2
    float4 a0 = {0,0,0,0}, a1 = {0,0,0,0}, a2 = {0,0,0,0}, a3 = {0,0,0,0};
    int i = s;
    for (; i + 7 < e; i += 8) {
        int s0 = csr[i + half], s1 = csr[i + 2 + half];
        int s2 = csr[i + 4 + half], s3 = csr[i + 6 + half];
        uint2 v0 = xv[(size_t)s0 * 32 + l];
        uint2 v1 = xv[(size_t)s1 * 32 + l];
        uint2 v2 = xv[(size_t)s2 * 32 + l];
        uint2 v3 = xv[(size_t)s3 * 32 + l];
        add4h(a0, v0); add4h(a1, v1); add4h(a2, v2); add4h(a3, v3);
    }
    for (; i + 1 < e; i += 2) {
        add4h(a0, xv[(size_t)csr[i + half] * 32 + l]);
    }
    if (i < e && half == 0) {
        add4h(a0, xv[(size_t)csr[i] * 32 + l]);
    }
    a0.x += a1.x + a2.x + a3.x; a0.y += a1.y + a2.y + a3.y;
    a0.z += a1.z + a2.z + a3.z; a0.w += a1.w + a2.w + a3.w;
    a0.x += __shfl_xor(a0.x, 32, 64);
    a0.y += __shfl_xor(a0.y, 32, 64);
    a0.z += __shfl_xor(a0.z, 32, 64);
    a0.w += __shfl_xor(a0.w, 32, 64);
    if (half == 0) {
        float dinv = 1.f / fmaxf((float)(e - s), 1.f);
        uint2 o;
        o.x = __half_as_ushort(__float2half(a0.x * dinv)) |
              ((unsigned)__half_as_ushort(__float2half(a0.y * dinv)) << 16);
        o.y = __half_as_ushort(__float2half(a0.z * dinv)) |
              ((unsigned)__half_as_ushort(__float2half(a0.w * dinv)) << 16);
        ((uint2*)outh)[(size_t)n * 32 + l] = o;
    }
}

// ---------------- fp16 MFMA GEMM (R9-proven): C = A @ W^T (+bias,relu), fp16 out ----------
// 2-pass split: A*(Wh+Wl), Wl = f16 residual of fp32 w -> ~2^-22 weight error.
// 4 waves in 2x2 over (32*MI)x(32*NJ) tile; fragments straight from global;
// double-buffered register prefetch. K % 64 == 0.
template<int MI, int NJ, bool RELU_BIAS>
__global__ __launch_bounds__(256) void gemm_f16(const ushort* __restrict__ A,
                                                const ushort* __restrict__ Wh,
                                                const ushort* __restrict__ Wl,
                                                const float* __restrict__ bias,
                                                ushort* __restrict__ C,
                                                int M, int N, int K) {
    int t = threadIdx.x;
    int wv = t >> 6, l = t & 63;
    int r = l & 15, q = l >> 4;
    int m0 = blockIdx.x * (32 * MI) + (wv >> 1) * (16 * MI);
    int n0 = blockIdx.y * (32 * NJ) + (wv & 1) * (16 * NJ);
    const _Float16* Af = (const _Float16*)A;
    const _Float16* Whf = (const _Float16*)Wh;
    const _Float16* Wlf = (const _Float16*)Wl;

    f32x4 acc[MI][NJ];
#pragma unroll
    for (int i = 0; i < MI; i++)
#pragma unroll
        for (int j = 0; j < NJ; j++) acc[i][j] = (f32x4){0.f, 0.f, 0.f, 0.f};

    f16x8 a0[MI], h0[NJ], l0[NJ], a1[MI], h1_[NJ], l1_[NJ];

    auto load = [&](f16x8* a, f16x8* wh, f16x8* wl, int k0) {
        int kf = k0 + q * 8;
#pragma unroll
        for (int i = 0; i < MI; i++) {
            int m = m0 + 16 * i + r;
            if (m > M - 1) m = M - 1;           // clamp tail (stores guarded)
            a[i] = *(const f16x8*)(Af + (size_t)m * K + kf);
        }
#pragma unroll
        for (int j = 0; j < NJ; j++) {
            size_t wo = (size_t)(n0 + 16 * j + r) * K + kf;
            wh[j] = *(const f16x8*)(Whf + wo);
            wl[j] = *(const f16x8*)(Wlf + wo);
        }
    };
    auto mm = [&](f16x8* a, f16x8* wh, f16x8* wl) {
#pragma unroll
        for (int i = 0; i < MI; i++)
#pragma unroll
            for (int j = 0; j < NJ; j++) {
                acc[i][j] = __builtin_amdgcn_mfma_f32_16x16x32_f16(a[i], wh[j], acc[i][j], 0, 0, 0);
                acc[i][j] = __builtin_amdgcn_mfma_f32_16x16x32_f16(a[i], wl[j], acc[i][j], 0, 0, 0);
            }
    };

    load(a0, h0, l0, 0);
    for (int k0 = 0; k0 < K; k0 += 64) {
        load(a1, h1_, l1_, k0 + 32);
        mm(a0, h0, l0);
        if (k0 + 64 < K) load(a0, h0, l0, k0 + 64);
        mm(a1, h1_, l1_);
    }

#pragma unroll
    for (int i = 0; i < MI; i++) {
#pragma unroll
        for (int reg = 0; reg < 4; reg++) {
            int m = m0 + 16 * i + q * 4 + reg;
            if (m < M) {
#pragma unroll
                for (int j = 0; j < NJ; j++) {
                    int n = n0 + 16 * j + r;
                    float v = acc[i][j][reg];
                    if (RELU_BIAS) v = fmaxf(v + bias[n], 0.f);
                    C[(size_t)m * N + n] = __half_as_ushort(__float2half(v));
                }
            }
        }
    }
}

// ------- Layer 2 agg (R8/R9-proven): fp16 z + fused bias+relu + [128]->[2] GEMM -------
__global__ __launch_bounds__(256) void agg2_out(const ushort* __restrict__ zh,
                                                const int* __restrict__ rp,
                                                const int* __restrict__ csr,
                                                const float* __restrict__ b2,
                                                const float* __restrict__ W3,
                                                const float* __restrict__ b3,
                                                float* __restrict__ out, int N) {
    int w = threadIdx.x >> 6, lane = threadIdx.x & 63;
    int n = blockIdx.x * 4 + w;
    if (n >= N) return;
    int s = rp[n], e = rp[n + 1];
    int half = lane >> 5, l = lane & 31;
    const uint2* zv = (const uint2*)zh;
    float4 a0 = {0,0,0,0}, a1 = {0,0,0,0}, a2 = {0,0,0,0}, a3 = {0,0,0,0};
    int i = s;
    for (; i + 7 < e; i += 8) {
        int s0 = csr[i + half], s1 = csr[i + 2 + half];
        int s2 = csr[i + 4 + half], s3 = csr[i + 6 + half];
        uint2 v0 = zv[(size_t)s0 * 32 + l];
        uint2 v1 = zv[(size_t)s1 * 32 + l];
        uint2 v2 = zv[(size_t)s2 * 32 + l];
        uint2 v3 = zv[(size_t)s3 * 32 + l];
        add4h(a0, v0); add4h(a1, v1); add4h(a2, v2); add4h(a3, v3);
    }
    for (; i + 1 < e; i += 2) {
        add4h(a0, zv[(size_t)csr[i + half] * 32 + l]);
    }
    if (i < e && half == 0) {
        add4h(a0, zv[(size_t)csr[i] * 32 + l]);
    }
    a0.x += a1.x + a2.x + a3.x; a0.y += a1.y + a2.y + a3.y;
    a0.z += a1.z + a2.z + a3.z; a0.w += a1.w + a2.w + a3.w;
    a0.x += __shfl_xor(a0.x, 32, 64);
    a0.y += __shfl_xor(a0.y, 32, 64);
    a0.z += __shfl_xor(a0.z, 32, 64);
    a0.w += __shfl_xor(a0.w, 32, 64);
    float dinv = 1.f / fmaxf((float)(e - s), 1.f);
    float4 bb = ((const float4*)b2)[l];
    float4 ww = ((const float4*)W3)[half * 32 + l];
    float hx = fmaxf(a0.x * dinv + bb.x, 0.f);
    float hy = fmaxf(a0.y * dinv + bb.y, 0.f);
    float hz = fmaxf(a0.z * dinv + bb.z, 0.f);
    float hw = fmaxf(a0.w * dinv + bb.w, 0.f);
    float p = hx * ww.x + hy * ww.y + hz * ww.z + hw * ww.w;
#pragma unroll
    for (int d = 16; d > 0; d >>= 1) p += __shfl_xor(p, d, 64);
    if (l == 0) out[(size_t)n * 2 + half] = p + b3[half];
}

extern "C" void kernel_launch(void* const* d_in, const int* in_sizes, int n_in,
                              void* d_out, int out_size, void* d_ws, size_t ws_size,
                              hipStream_t stream) {
    const float* x  = (const float*)d_in[0];
    const int*   ei = (const int*)d_in[1];
    const float* W1 = (const float*)d_in[3];
    const float* b1 = (const float*)d_in[4];
    const float* W2 = (const float*)d_in[5];
    const float* b2 = (const float*)d_in[6];
    const float* W3 = (const float*)d_in[7];
    const float* b3 = (const float*)d_in[8];
    float* out = (float*)d_out;

    int N = in_sizes[0] / IN_F;   // 50000
    int E = in_sizes[1] / 2;      // 800000
    const int* row = ei;
    const int* col = ei + E;

    char* base = (char*)d_ws;
    size_t off = 0;
    auto alloc = [&](size_t bytes) -> void* {
        off = (off + 255) & ~(size_t)255;
        void* p = base + off;
        off += bytes;
        return p;
    };
    // zeroed region: deg | fill
    int*    deg  = (int*)alloc((size_t)2 * N * 4);
    int*    fill = deg + N;
    int*    rp   = (int*)alloc((size_t)(N + 1) * 4);
    int*    tmp  = (int*)alloc((size_t)N * 4);
    int*    bsum = (int*)alloc(1024);
    int*    csr  = (int*)alloc((size_t)E * 4);
    ushort* xh   = (ushort*)alloc((size_t)N * IN_F * 2);
    ushort* f2h  = (ushort*)alloc((size_t)N * IN_F * 2);   // agg1 out fp16
    ushort* h1h  = (ushort*)alloc((size_t)N * HID * 2);    // layer1 out fp16
    ushort* z2h  = (ushort*)alloc((size_t)N * HID2 * 2);   // gemm2 out fp16
    ushort* w1h  = (ushort*)alloc(HID * IN_F * 2);
    ushort* w1l  = (ushort*)alloc(HID * IN_F * 2);
    ushort* w2h  = (ushort*)alloc(HID2 * HID * 2);
    ushort* w2l  = (ushort*)alloc(HID2 * HID * 2);

    hipMemsetAsync(deg, 0, (size_t)2 * N * 4, stream);

    int eb = (E + 255) / 256;   // 3125
    int nb = (N + 255) / 256;   // 196
    prep<<<2048, 256, 0, stream>>>(x, col, W1, W2, xh, w1h, w1l, w2h, w2l, deg, N, E);
    scan_block<<<nb, 256, 0, stream>>>(deg, tmp, bsum, N);
    scan_bsums<<<1, 256, 0, stream>>>(bsum, nb);
    scan_add<<<nb, 256, 0, stream>>>(tmp, bsum, rp, N);
    fill_csr<<<eb, 256, 0, stream>>>(row, col, rp, fill, csr, E);

    agg_gather<<<(N + 3) / 4, 256, 0, stream>>>(xh, rp, csr, f2h, N);

    // gemm1: 128x128 tiles, grid (391, 2); gemm2: 64x64 tiles, grid (782, 2)
    gemm_f16<4, 4, true><<<dim3((N + 127) / 128, HID / 128), 256, 0, stream>>>(
        f2h, w1h, w1l, b1, h1h, N, HID, IN_F);
    gemm_f16<2, 2, false><<<dim3((N + 63) / 64, HID2 / 64), 256, 0, stream>>>(
        h1h, w2h, w2l, nullptr, z2h, N, HID2, HID);

    agg2_out<<<(N + 3) / 4, 256, 0, stream>>>(z2h, rp, csr, b2, W3, b3, out, N);
}